// Round 4
// baseline (363.113 us; speedup 1.0000x reference)
//
#include <hip/hip_runtime.h>
#include <hip/hip_bf16.h>
#include <math.h>

typedef __attribute__((ext_vector_type(8))) short short8;   // 8 bf16 = one MFMA A/B frag
typedef __attribute__((ext_vector_type(4))) float f32x4;    // MFMA C/D frag

#define MFMA16x16x32(A,B,C) __builtin_amdgcn_mfma_f32_16x16x32_bf16((A),(B),(C),0,0,0)

__device__ __forceinline__ short f2b(float x) {
  __hip_bfloat16 h = __float2bfloat16(x);
  short s; __builtin_memcpy(&s, &h, 2); return s;
}
__device__ __forceinline__ float b2f(short s) {
  __hip_bfloat16 h; __builtin_memcpy(&h, &s, 2); return __bfloat162float(h);
}

// ---------------------------------------------------------------------------
// prep: blocks 0..63 pack the 4 weights [512][512] fp32 -> bf16 MFMA B-frag
// order: elem index = ((kf*32 + nf)*64 + lane)*8 + jj, where lane holds
// (n = nf*16 + lane%16, k = kf*32 + 8*(lane/16) + jj). block 64: softplus(scale).
// ---------------------------------------------------------------------------
__global__ __launch_bounds__(256)
void prep_kernel(const float* __restrict__ Wq, const float* __restrict__ Wk,
                 const float* __restrict__ Wv, const float* __restrict__ Wp,
                 const float* __restrict__ scale,
                 short* __restrict__ wpack, float* __restrict__ spls)
{
  const int b = blockIdx.x;
  const int t = threadIdx.x;
  if (b == 64) {
    for (int i = t; i < 512; i += 256) {
      float x = scale[i];
      spls[i] = (x > 20.f) ? x : log1pf(expf(x));
    }
    return;
  }
  const float* Ws[4] = {Wq, Wk, Wv, Wp};
  const int w = b >> 4, kf16 = b & 15;
  const float* W = Ws[w];
  short* dst = wpack + (size_t)w * (512 * 512);
  __shared__ short lds[32 * 512];
  for (int i = 0; i < 64; ++i) {
    int idx = i * 256 + t;              // 0..16383
    int r = idx >> 9, c = idx & 511;
    lds[idx] = f2b(W[(size_t)(kf16 * 32 + r) * 512 + c]);
  }
  __syncthreads();
  for (int s = 0; s < 8; ++s) {
    int slot = s * 256 + t;             // 0..2047 = 32 nfrags x 64 lanes
    int nf = slot >> 6, l = slot & 63;
    int n = nf * 16 + (l & 15);
    int k0 = 8 * (l >> 4);
    short8 v;
#pragma unroll
    for (int jj = 0; jj < 8; ++jj) v[jj] = lds[(k0 + jj) * 512 + n];
    *(short8*)(dst + ((size_t)(kf16 * 32 + nf) * 64 + l) * 8) = v;
  }
}

// ---------------------------------------------------------------------------
// proj v2: one block = 64 rows x 512 cols; 8 waves each owning a 64x64 tile
// (4x4 acc frags). B-frags stream directly from L2 (wpack is 512KB, L2-fits;
// each frag read by exactly one wave per block -> LDS staging would add a
// pure-overhead hop). A (activations) from global, L1-shared across waves.
// NO barriers in the k-loop -> compiler software-pipelines freely.
// MODE 0: q -> relu,+eps,/s,focus -> row-major bf16.
// MODE 1: k -> same epilogue -> k-major frag pack. MODE 2: v -> plain pack.
// MODE 3: A bf16 row-major, out = A@W + bp (fp32).
// ---------------------------------------------------------------------------
template<int MODE>
__global__ __launch_bounds__(512, 2)
void proj_kernel(const void* __restrict__ Xv, const short* __restrict__ wpk,
                 const float* __restrict__ spls, short* __restrict__ outp,
                 const float* __restrict__ bp, float* __restrict__ outf)
{
  __shared__ short tile[64 * 512];      // 64KB bounce, XOR-swizzled
  __shared__ float pnorm[2][8][64];     // per-wave row-norm partials
  __shared__ float facs[64];
  const int t = threadIdx.x;
  const int lane = t & 63;
  const int wid = t >> 6;               // wave owns cols [wid*64, wid*64+64)
  const int g = lane >> 4;
  const int cl = lane & 15;
  const int rb = blockIdx.x << 6;

  const float* Xf = (const float*)Xv;
  const short* Xb = (const short*)Xv;

  f32x4 zero4 = {0.f, 0.f, 0.f, 0.f};
  f32x4 acc[4][4];                      // [row-frag][col-frag]
#pragma unroll
  for (int rf = 0; rf < 4; ++rf)
#pragma unroll
    for (int cf = 0; cf < 4; ++cf) acc[rf][cf] = zero4;

  const short8* wp8 = (const short8*)wpk;

#pragma unroll 4
  for (int kf = 0; kf < 16; ++kf) {
    short8 bfr[4];
#pragma unroll
    for (int cf = 0; cf < 4; ++cf)
      bfr[cf] = wp8[((size_t)(kf * 32 + wid * 4 + cf)) * 64 + lane];
    short8 af[4];
#pragma unroll
    for (int rf = 0; rf < 4; ++rf) {
      if (MODE < 3) {
        const float* ap = Xf + (size_t)(rb + rf * 16 + cl) * 512 + kf * 32 + 8 * g;
        f32x4 a0 = *(const f32x4*)ap;
        f32x4 a1 = *(const f32x4*)(ap + 4);
#pragma unroll
        for (int j = 0; j < 4; ++j) { af[rf][j] = f2b(a0[j]); af[rf][4 + j] = f2b(a1[j]); }
      } else {
        af[rf] = *(const short8*)(Xb + (size_t)(rb + rf * 16 + cl) * 512 + kf * 32 + 8 * g);
      }
    }
#pragma unroll
    for (int rf = 0; rf < 4; ++rf)
#pragma unroll
      for (int cf = 0; cf < 4; ++cf)
        acc[rf][cf] = MFMA16x16x32(af[rf], bfr[cf], acc[rf][cf]);
  }

  if (MODE == 3) {
    // direct fp32 store + bias
#pragma unroll
    for (int rf = 0; rf < 4; ++rf)
#pragma unroll
      for (int cf = 0; cf < 4; ++cf) {
        int c = wid * 64 + cf * 16 + cl;
        float bv = bp[c];
#pragma unroll
        for (int j = 0; j < 4; ++j)
          outf[(size_t)(rb + rf * 16 + 4 * g + j) * 512 + c] = acc[rf][cf][j] + bv;
      }
    return;
  }

  if (MODE < 2) {
    // epilogue: y = (relu(acc)+eps)/softplus(s); row-wise sum(y^2), sum(y^6)
    float sp_inv[4];
#pragma unroll
    for (int cf = 0; cf < 4; ++cf) sp_inv[cf] = 1.f / spls[wid * 64 + cf * 16 + cl];
    float p2[4][4], p6[4][4];
#pragma unroll
    for (int rf = 0; rf < 4; ++rf)
#pragma unroll
      for (int j = 0; j < 4; ++j) { p2[rf][j] = 0.f; p6[rf][j] = 0.f; }
#pragma unroll
    for (int rf = 0; rf < 4; ++rf)
#pragma unroll
      for (int cf = 0; cf < 4; ++cf)
#pragma unroll
        for (int j = 0; j < 4; ++j) {
          float v = acc[rf][cf][j];
          v = fmaxf(v, 0.f) + 1e-6f;
          v *= sp_inv[cf];
          acc[rf][cf][j] = v;
          float v2 = v * v;
          p2[rf][j] += v2;
          p6[rf][j] += v2 * v2 * v2;
        }
    // reduce across the 16 lanes sharing each row (cl bits = lane bits 0..3)
#pragma unroll
    for (int m = 1; m < 16; m <<= 1) {
#pragma unroll
      for (int rf = 0; rf < 4; ++rf)
#pragma unroll
        for (int j = 0; j < 4; ++j) {
          p2[rf][j] += __shfl_xor(p2[rf][j], m, 64);
          p6[rf][j] += __shfl_xor(p6[rf][j], m, 64);
        }
    }
    if (cl == 0) {
#pragma unroll
      for (int rf = 0; rf < 4; ++rf)
#pragma unroll
        for (int j = 0; j < 4; ++j) {
          pnorm[0][wid][rf * 16 + 4 * g + j] = p2[rf][j];
          pnorm[1][wid][rf * 16 + 4 * g + j] = p6[rf][j];
        }
    }
    __syncthreads();
    if (t < 64) {
      float a = 0.f, b = 0.f;
#pragma unroll
      for (int w = 0; w < 8; ++w) { a += pnorm[0][w][t]; b += pnorm[1][w][t]; }
      facs[t] = sqrtf(a / b);           // ||y|| / ||y^3||
    }
    __syncthreads();
    float fac[4][4];
#pragma unroll
    for (int rf = 0; rf < 4; ++rf)
#pragma unroll
      for (int j = 0; j < 4; ++j) fac[rf][j] = facs[rf * 16 + 4 * g + j];
#pragma unroll
    for (int rf = 0; rf < 4; ++rf)
#pragma unroll
      for (int cf = 0; cf < 4; ++cf)
#pragma unroll
        for (int j = 0; j < 4; ++j) {
          float v = acc[rf][cf][j];
          float o = v * v * v * fac[rf][j];
          int r = rf * 16 + 4 * g + j;
          int c = wid * 64 + cf * 16 + cl;
          int byteoff = (r * 1024 + c * 2) ^ ((r & 7) << 4);
          *(short*)((char*)tile + byteoff) = f2b(o);
        }
  } else {
#pragma unroll
    for (int rf = 0; rf < 4; ++rf)
#pragma unroll
      for (int cf = 0; cf < 4; ++cf)
#pragma unroll
        for (int j = 0; j < 4; ++j) {
          int r = rf * 16 + 4 * g + j;
          int c = wid * 64 + cf * 16 + cl;
          int byteoff = (r * 1024 + c * 2) ^ ((r & 7) << 4);
          *(short*)((char*)tile + byteoff) = f2b(acc[rf][cf][j]);
        }
  }
  __syncthreads();

  if (MODE == 0) {
    // coalesced row-major store
    const int r = t >> 3;
    const int c8 = t & 7;
#pragma unroll
    for (int s = 0; s < 8; ++s) {
      int ci = c8 + 8 * s;
      int byteoff = (r * 1024 + ci * 16) ^ ((r & 7) << 4);
      short8 v = *(const short8*)((const char*)tile + byteoff);
      *(short8*)(outp + (size_t)(rb + r) * 512 + ci * 8) = v;
    }
  } else {
    // k-major fragment pack store
    const int l = lane;
    const int batch = rb >> 12;
    const int jf_base = (rb & 4095) >> 5;
#pragma unroll
    for (int s = 0; s < 8; ++s) {
      int fidx = wid * 8 + s;           // 0..63 = 2 jfrag x 32 cfrag
      int jf = fidx >> 5;
      int cf = fidx & 31;
      int c = cf * 16 + (l & 15);
      int j0 = jf * 32 + 8 * (l >> 4);
      short8 v;
#pragma unroll
      for (int jj = 0; jj < 8; ++jj) {
        int j = j0 + jj;
        int byteoff = (j * 1024 + c * 2) ^ ((j & 7) << 4);
        v[jj] = *(const short*)((const char*)tile + byteoff);
      }
      int bh = batch * 8 + (cf >> 2);
      int cfh = cf & 3;
      int jfg = jf_base + jf;
      *(short8*)(outp + (((size_t)(bh * 128 + jfg) * 4 + cfh) * 64 + l) * 8) = v;
    }
  }
}

// ---------------------------------------------------------------------------
// kv: block = (bh, split of 512 tokens); 4 waves x 4 jfg chunks each.
// Register-accumulated MFMA (no atomics); cross-wave reduce via private LDS
// slots; one fp32 partial per block. ksum accumulated in regs alongside.
// ---------------------------------------------------------------------------
__global__ __launch_bounds__(256)
void kv_kernel(const short* __restrict__ kpack, const short* __restrict__ vpack,
               float* __restrict__ pKV, float* __restrict__ pKS)
{
  __shared__ float red[4][64 * 64];    // 64KB: per-wave partial kv tiles
  __shared__ float ksacc[64];
  const int t = threadIdx.x;
  const int lane = t & 63;
  const int w = t >> 6;
  const int g = lane >> 4;
  const int cl = lane & 15;
  const int bh = blockIdx.x >> 3;
  const int sp = blockIdx.x & 7;
  if (t < 64) ksacc[t] = 0.f;
  __syncthreads();

  f32x4 zero4 = {0.f, 0.f, 0.f, 0.f};
  f32x4 acc[4][4];
#pragma unroll
  for (int df = 0; df < 4; ++df)
#pragma unroll
    for (int cf = 0; cf < 4; ++cf) acc[df][cf] = zero4;
  float ks[4] = {0.f, 0.f, 0.f, 0.f};
  const short8* kp = (const short8*)kpack;
  const short8* vp = (const short8*)vpack;

#pragma unroll
  for (int i = 0; i < 4; ++i) {
    int jfg = sp * 16 + w * 4 + i;
    size_t base = ((size_t)bh * 128 + jfg) * 4 * 64;
    short8 afr[4], bfr[4];
#pragma unroll
    for (int f = 0; f < 4; ++f) {
      afr[f] = vp[base + (size_t)f * 64 + lane];
      bfr[f] = kp[base + (size_t)f * 64 + lane];
    }
#pragma unroll
    for (int cf = 0; cf < 4; ++cf) {
      float s = 0.f;
#pragma unroll
      for (int jj = 0; jj < 8; ++jj) s += b2f(bfr[cf][jj]);
      ks[cf] += s;
    }
#pragma unroll
    for (int df = 0; df < 4; ++df)
#pragma unroll
      for (int cf = 0; cf < 4; ++cf)
        acc[df][cf] = MFMA16x16x32(afr[df], bfr[cf], acc[df][cf]);
  }

  // ksum: reduce over lanes sharing the same cl (g dimension)
#pragma unroll
  for (int cf = 0; cf < 4; ++cf) {
    ks[cf] += __shfl_xor(ks[cf], 16, 64);
    ks[cf] += __shfl_xor(ks[cf], 32, 64);
  }
  if (lane < 16) {
#pragma unroll
    for (int cf = 0; cf < 4; ++cf) atomicAdd(&ksacc[cf * 16 + lane], ks[cf]);
  }

  // write per-wave tile to its private LDS slot (no atomics)
#pragma unroll
  for (int df = 0; df < 4; ++df)
#pragma unroll
    for (int cf = 0; cf < 4; ++cf)
#pragma unroll
      for (int j = 0; j < 4; ++j)
        red[w][(df * 16 + 4 * g + j) * 64 + cf * 16 + cl] = acc[df][cf][j];
  __syncthreads();

  // cross-wave reduce + partial store
  float* dkv = pKV + (size_t)blockIdx.x * 4096;
  for (int i = t; i < 4096; i += 256)
    dkv[i] = red[0][i] + red[1][i] + red[2][i] + red[3][i];
  if (t < 64) pKS[(size_t)blockIdx.x * 64 + t] = ksacc[t];
}

__global__ __launch_bounds__(256)
void kv_reduce(const float* __restrict__ pKV, const float* __restrict__ pKS,
               short* __restrict__ kvT, float* __restrict__ ksum)
{
  const int bh = blockIdx.x;
  const int t = threadIdx.x;
  for (int i = t; i < 4096; i += 256) {
    float s = 0.f;
#pragma unroll
    for (int sp = 0; sp < 8; ++sp) s += pKV[(size_t)(bh * 8 + sp) * 4096 + i];
    kvT[(size_t)bh * 4096 + i] = f2b(s);
  }
  if (t < 64) {
    float s = 0.f;
#pragma unroll
    for (int sp = 0; sp < 8; ++sp) s += pKS[(size_t)(bh * 8 + sp) * 64 + t];
    ksum[bh * 64 + t] = s;
  }
}

// ---------------------------------------------------------------------------
// x: per block (64 rows): z from q.ksum; x = z * q @ kv per head via MFMA
// (kvT gives contiguous B-frags); x -> swizzled LDS -> row-major bf16 store.
// ---------------------------------------------------------------------------
__global__ __launch_bounds__(512)
void x_kernel(const short* __restrict__ qf, const short* __restrict__ kvT,
              const float* __restrict__ ksum, short* __restrict__ xout)
{
  __shared__ short xt[64 * 512];
  __shared__ float ksb[512];
  __shared__ float zb[64 * 8];
  const int t = threadIdx.x;
  const int lane = t & 63;
  const int wid = t >> 6;
  const int wr = wid >> 1;
  const int wc = wid & 1;
  const int g = lane >> 4;
  const int cl = lane & 15;
  const int rb = blockIdx.x << 6;
  const int batch = rb >> 12;

  ksb[t] = ksum[batch * 512 + t];
  __syncthreads();

  // z: one (row, head) pair per thread
  {
    int r = t >> 3, h = t & 7;
    const short8* qrow = (const short8*)(qf + (size_t)(rb + r) * 512 + h * 64);
    float d = 0.f;
#pragma unroll
    for (int c8 = 0; c8 < 8; ++c8) {
      short8 qv = qrow[c8];
#pragma unroll
      for (int jj = 0; jj < 8; ++jj) d += b2f(qv[jj]) * ksb[h * 64 + c8 * 8 + jj];
    }
    zb[r * 8 + h] = 1.f / (d + 1e-6f);
  }
  __syncthreads();

  f32x4 zero4 = {0.f, 0.f, 0.f, 0.f};
  f32x4 xacc[16];
#pragma unroll
  for (int i = 0; i < 16; ++i) xacc[i] = zero4;

  const short8* q8 = (const short8*)qf;
  const size_t qrowbase = (size_t)(rb + wr * 16 + cl) * 64;  // row * 512 / 8
#pragma unroll
  for (int hh = 0; hh < 4; ++hh) {
    int h = wc * 4 + hh;
    short8 af0 = q8[qrowbase + h * 8 + g];
    short8 af1 = q8[qrowbase + h * 8 + 4 + g];
    const short8* kv8 = (const short8*)kvT + ((size_t)(batch * 8 + h)) * 512;
#pragma unroll
    for (int nfl = 0; nfl < 4; ++nfl) {
      short8 b0 = kv8[(size_t)(nfl * 16 + cl) * 8 + g];
      short8 b1 = kv8[(size_t)(nfl * 16 + cl) * 8 + 4 + g];
      int nf = hh * 4 + nfl;
      xacc[nf] = MFMA16x16x32(af0, b0, xacc[nf]);
      xacc[nf] = MFMA16x16x32(af1, b1, xacc[nf]);
    }
  }
  // scale by z and stash x (bf16, swizzled)
#pragma unroll
  for (int hh = 0; hh < 4; ++hh) {
    int h = wc * 4 + hh;
    float z4[4];
#pragma unroll
    for (int j = 0; j < 4; ++j) z4[j] = zb[(wr * 16 + 4 * g + j) * 8 + h];
#pragma unroll
    for (int nfl = 0; nfl < 4; ++nfl) {
      int nf = hh * 4 + nfl;
#pragma unroll
      for (int j = 0; j < 4; ++j) {
        float xv = xacc[nf][j] * z4[j];
        int r = wr * 16 + 4 * g + j;
        int c = wc * 256 + nf * 16 + cl;
        int byteoff = (r * 1024 + c * 2) ^ ((r & 7) << 4);
        *(short*)((char*)xt + byteoff) = f2b(xv);
      }
    }
  }
  __syncthreads();

  // coalesced row-major store
  const int r = t >> 3;
  const int c8 = t & 7;
#pragma unroll
  for (int s = 0; s < 8; ++s) {
    int ci = c8 + 8 * s;
    int byteoff = (r * 1024 + ci * 16) ^ ((r & 7) << 4);
    short8 v = *(const short8*)((const char*)xt + byteoff);
    *(short8*)(xout + (size_t)(rb + r) * 512 + ci * 8) = v;
  }
}

// ---------------------------------------------------------------------------
extern "C" void kernel_launch(void* const* d_in, const int* in_sizes, int n_in,
                              void* d_out, int out_size, void* d_ws, size_t ws_size,
                              hipStream_t stream)
{
  const float* query  = (const float*)d_in[0];
  const float* key_in = (const float*)d_in[1];
  const float* value  = (const float*)d_in[2];
  const float* Wq     = (const float*)d_in[3];
  const float* Wk     = (const float*)d_in[4];
  const float* Wv     = (const float*)d_in[5];
  const float* Wp     = (const float*)d_in[6];
  const float* bp     = (const float*)d_in[7];
  const float* scale  = (const float*)d_in[8];
  float* out = (float*)d_out;

  char* ws = (char*)d_ws;
  size_t off = 0;
  auto alloc = [&](size_t bytes) -> void* {
    void* p = ws + off;
    off += (bytes + 255) & ~(size_t)255;
    return p;
  };
  float* spls  = (float*)alloc(512 * 4);
  short* wpack = (short*)alloc((size_t)4 * 512 * 512 * 2);
  short* qf    = (short*)alloc((size_t)32768 * 512 * 2);
  short* kpack = (short*)alloc((size_t)32768 * 512 * 2);
  short* vpack = (short*)alloc((size_t)32768 * 512 * 2);
  float* pKV   = (float*)alloc((size_t)512 * 4096 * 4);
  float* pKS   = (float*)alloc((size_t)512 * 64 * 4);
  short* kvT   = (short*)alloc((size_t)64 * 4096 * 2);
  float* ksum  = (float*)alloc((size_t)64 * 64 * 4);
  // x reuses kpack: kpack is dead after kv_kernel, x_kernel runs after kv_reduce
  short* xbuf  = kpack;

  prep_kernel<<<65, 256, 0, stream>>>(Wq, Wk, Wv, Wp, scale, wpack, spls);
  proj_kernel<0><<<512, 512, 0, stream>>>(query,  wpack + (size_t)0 * 512 * 512, spls, qf,    nullptr, nullptr);
  proj_kernel<1><<<512, 512, 0, stream>>>(key_in, wpack + (size_t)1 * 512 * 512, spls, kpack, nullptr, nullptr);
  proj_kernel<2><<<512, 512, 0, stream>>>(value,  wpack + (size_t)2 * 512 * 512, spls, vpack, nullptr, nullptr);
  kv_kernel<<<512, 256, 0, stream>>>(kpack, vpack, pKV, pKS);
  kv_reduce<<<64, 256, 0, stream>>>(pKV, pKS, kvT, ksum);
  x_kernel<<<512, 512, 0, stream>>>(qf, kvT, ksum, xbuf);
  proj_kernel<3><<<512, 512, 0, stream>>>(xbuf, wpack + (size_t)3 * 512 * 512, spls, nullptr, bp, out);
}

// Round 5
// 210.720 us; speedup vs baseline: 1.7232x; 1.7232x over previous
//
#include <hip/hip_runtime.h>
#include <hip/hip_bf16.h>
#include <math.h>

typedef __attribute__((ext_vector_type(8))) short short8;   // 8 bf16 = one MFMA A/B frag
typedef __attribute__((ext_vector_type(4))) float f32x4;    // MFMA C/D frag

#define MFMA16x16x32(A,B,C) __builtin_amdgcn_mfma_f32_16x16x32_bf16((A),(B),(C),0,0,0)

__device__ __forceinline__ short f2b(float x) {
  __hip_bfloat16 h = __float2bfloat16(x);
  short s; __builtin_memcpy(&s, &h, 2); return s;
}
__device__ __forceinline__ float b2f(short s) {
  __hip_bfloat16 h; __builtin_memcpy(&h, &s, 2); return __bfloat162float(h);
}

// ---------------------------------------------------------------------------
// prep: blocks 0..63 pack the 4 weights [512][512] fp32 -> bf16 MFMA B-frag
// order: elem index = ((kf*32 + nf)*64 + lane)*8 + jj, where lane holds
// (n = nf*16 + lane%16, k = kf*32 + 8*(lane/16) + jj). block 64: softplus(scale).
// ---------------------------------------------------------------------------
__global__ __launch_bounds__(256)
void prep_kernel(const float* __restrict__ Wq, const float* __restrict__ Wk,
                 const float* __restrict__ Wv, const float* __restrict__ Wp,
                 const float* __restrict__ scale,
                 short* __restrict__ wpack, float* __restrict__ spls)
{
  const int b = blockIdx.x;
  const int t = threadIdx.x;
  if (b == 64) {
    for (int i = t; i < 512; i += 256) {
      float x = scale[i];
      spls[i] = (x > 20.f) ? x : log1pf(expf(x));
    }
    return;
  }
  const float* Ws[4] = {Wq, Wk, Wv, Wp};
  const int w = b >> 4, kf16 = b & 15;
  const float* W = Ws[w];
  short* dst = wpack + (size_t)w * (512 * 512);
  __shared__ short lds[32 * 512];
  for (int i = 0; i < 64; ++i) {
    int idx = i * 256 + t;              // 0..16383
    int r = idx >> 9, c = idx & 511;
    lds[idx] = f2b(W[(size_t)(kf16 * 32 + r) * 512 + c]);
  }
  __syncthreads();
  for (int s = 0; s < 8; ++s) {
    int slot = s * 256 + t;             // 0..2047 = 32 nfrags x 64 lanes
    int nf = slot >> 6, l = slot & 63;
    int n = nf * 16 + (l & 15);
    int k0 = 8 * (l >> 4);
    short8 v;
#pragma unroll
    for (int jj = 0; jj < 8; ++jj) v[jj] = lds[(k0 + jj) * 512 + n];
    *(short8*)(dst + ((size_t)(kf16 * 32 + nf) * 64 + l) * 8) = v;
  }
}

// ---------------------------------------------------------------------------
// proj v3: one block = 64 rows x 512 cols; 8 waves each owning a 64x64 tile
// (4x4 acc frags). A-tile staged ONCE into swizzled LDS (coalesced fp32 read,
// bf16 convert); k-loop reads A via ds_read_b128 (<=2-way conflicts) and
// streams B-frags from L2 (wpack 512KB, L2-pinned; each frag read by exactly
// one wave per block) with a register double-buffer. NO k-loop barriers.
// A-tile LDS unions with the epilogue bounce tile.
// MODE 0: q -> relu,+eps,/s,focus -> row-major bf16.
// MODE 1: k -> same epilogue -> k-major frag pack. MODE 2: v -> plain pack.
// MODE 3: A bf16 row-major, out = A@W + bp (fp32).
// ---------------------------------------------------------------------------
template<int MODE>
__global__ __launch_bounds__(512, 2)
void proj_kernel(const void* __restrict__ Xv, const short* __restrict__ wpk,
                 const float* __restrict__ spls, short* __restrict__ outp,
                 const float* __restrict__ bp, float* __restrict__ outf)
{
  __shared__ short tile[64 * 512];      // 64KB: A-tile during k-loop, bounce after
  __shared__ float pnorm[2][8][64];     // per-wave row-norm partials
  __shared__ float facs[64];
  const int t = threadIdx.x;
  const int lane = t & 63;
  const int wid = t >> 6;               // wave owns cols [wid*64, wid*64+64)
  const int g = lane >> 4;
  const int cl = lane & 15;
  const int rb = blockIdx.x << 6;

  // ---- stage A tile (64 rows x 512 cols) into swizzled LDS as bf16 ----
  {
    const int r = t >> 3;               // 8 threads per row
    const int c8 = t & 7;
    if (MODE < 3) {
      const float* src = (const float*)Xv + (size_t)(rb + r) * 512;
#pragma unroll
      for (int s = 0; s < 8; ++s) {
        int c = s * 64 + c8 * 8;        // per s: 8 lanes cover 256B contiguous
        f32x4 a0 = *(const f32x4*)(src + c);
        f32x4 a1 = *(const f32x4*)(src + c + 4);
        short8 v;
#pragma unroll
        for (int j = 0; j < 4; ++j) { v[j] = f2b(a0[j]); v[4 + j] = f2b(a1[j]); }
        int byteoff = (r * 1024 + c * 2) ^ ((r & 7) << 4);
        *(short8*)((char*)tile + byteoff) = v;
      }
    } else {
      const short* src = (const short*)Xv + (size_t)(rb + r) * 512;
#pragma unroll
      for (int s = 0; s < 8; ++s) {
        int c = s * 64 + c8 * 8;
        short8 v = *(const short8*)(src + c);
        int byteoff = (r * 1024 + c * 2) ^ ((r & 7) << 4);
        *(short8*)((char*)tile + byteoff) = v;
      }
    }
  }
  __syncthreads();

  f32x4 zero4 = {0.f, 0.f, 0.f, 0.f};
  f32x4 acc[4][4];                      // [row-frag][col-frag]
#pragma unroll
  for (int rf = 0; rf < 4; ++rf)
#pragma unroll
    for (int cf = 0; cf < 4; ++cf) acc[rf][cf] = zero4;

  const short8* wp8 = (const short8*)wpk;

  // B register double-buffer; A from LDS; no barriers in the loop.
  short8 bcur[4], bnxt[4];
#pragma unroll
  for (int cf = 0; cf < 4; ++cf)
    bcur[cf] = wp8[((size_t)(wid * 4 + cf)) * 64 + lane];

  for (int kf = 0; kf < 16; ++kf) {
    if (kf < 15) {
#pragma unroll
      for (int cf = 0; cf < 4; ++cf)
        bnxt[cf] = wp8[((size_t)((kf + 1) * 32 + wid * 4 + cf)) * 64 + lane];
    }
    short8 af[4];
#pragma unroll
    for (int rf = 0; rf < 4; ++rf) {
      int row = rf * 16 + cl;
      int byteoff = (row * 1024 + (kf * 32 + 8 * g) * 2) ^ ((row & 7) << 4);
      af[rf] = *(const short8*)((const char*)tile + byteoff);
    }
#pragma unroll
    for (int rf = 0; rf < 4; ++rf)
#pragma unroll
      for (int cf = 0; cf < 4; ++cf)
        acc[rf][cf] = MFMA16x16x32(af[rf], bcur[cf], acc[rf][cf]);
    if (kf < 15) {
#pragma unroll
      for (int cf = 0; cf < 4; ++cf) bcur[cf] = bnxt[cf];
    }
  }

  if (MODE == 3) {
    // direct fp32 store + bias
#pragma unroll
    for (int rf = 0; rf < 4; ++rf)
#pragma unroll
      for (int cf = 0; cf < 4; ++cf) {
        int c = wid * 64 + cf * 16 + cl;
        float bv = bp[c];
#pragma unroll
        for (int j = 0; j < 4; ++j)
          outf[(size_t)(rb + rf * 16 + 4 * g + j) * 512 + c] = acc[rf][cf][j] + bv;
      }
    return;
  }

  if (MODE < 2) {
    // epilogue: y = (relu(acc)+eps)/softplus(s); row-wise sum(y^2), sum(y^6)
    float sp_inv[4];
#pragma unroll
    for (int cf = 0; cf < 4; ++cf) sp_inv[cf] = 1.f / spls[wid * 64 + cf * 16 + cl];
    float p2[4][4], p6[4][4];
#pragma unroll
    for (int rf = 0; rf < 4; ++rf)
#pragma unroll
      for (int j = 0; j < 4; ++j) { p2[rf][j] = 0.f; p6[rf][j] = 0.f; }
#pragma unroll
    for (int rf = 0; rf < 4; ++rf)
#pragma unroll
      for (int cf = 0; cf < 4; ++cf)
#pragma unroll
        for (int j = 0; j < 4; ++j) {
          float v = acc[rf][cf][j];
          v = fmaxf(v, 0.f) + 1e-6f;
          v *= sp_inv[cf];
          acc[rf][cf][j] = v;
          float v2 = v * v;
          p2[rf][j] += v2;
          p6[rf][j] += v2 * v2 * v2;
        }
    // reduce across the 16 lanes sharing each row (cl bits = lane bits 0..3)
#pragma unroll
    for (int m = 1; m < 16; m <<= 1) {
#pragma unroll
      for (int rf = 0; rf < 4; ++rf)
#pragma unroll
        for (int j = 0; j < 4; ++j) {
          p2[rf][j] += __shfl_xor(p2[rf][j], m, 64);
          p6[rf][j] += __shfl_xor(p6[rf][j], m, 64);
        }
    }
    if (cl == 0) {
#pragma unroll
      for (int rf = 0; rf < 4; ++rf)
#pragma unroll
        for (int j = 0; j < 4; ++j) {
          pnorm[0][wid][rf * 16 + 4 * g + j] = p2[rf][j];
          pnorm[1][wid][rf * 16 + 4 * g + j] = p6[rf][j];
        }
    }
    __syncthreads();                    // also: all A-tile reads complete here
    if (t < 64) {
      float a = 0.f, b = 0.f;
#pragma unroll
      for (int w = 0; w < 8; ++w) { a += pnorm[0][w][t]; b += pnorm[1][w][t]; }
      facs[t] = sqrtf(a / b);           // ||y|| / ||y^3||
    }
    __syncthreads();
    float fac[4][4];
#pragma unroll
    for (int rf = 0; rf < 4; ++rf)
#pragma unroll
      for (int j = 0; j < 4; ++j) fac[rf][j] = facs[rf * 16 + 4 * g + j];
#pragma unroll
    for (int rf = 0; rf < 4; ++rf)
#pragma unroll
      for (int cf = 0; cf < 4; ++cf)
#pragma unroll
        for (int j = 0; j < 4; ++j) {
          float v = acc[rf][cf][j];
          float o = v * v * v * fac[rf][j];
          int r = rf * 16 + 4 * g + j;
          int c = wid * 64 + cf * 16 + cl;
          int byteoff = (r * 1024 + c * 2) ^ ((r & 7) << 4);
          *(short*)((char*)tile + byteoff) = f2b(o);
        }
  } else {
    __syncthreads();                    // A-tile reads must finish before overwrite
#pragma unroll
    for (int rf = 0; rf < 4; ++rf)
#pragma unroll
      for (int cf = 0; cf < 4; ++cf)
#pragma unroll
        for (int j = 0; j < 4; ++j) {
          int r = rf * 16 + 4 * g + j;
          int c = wid * 64 + cf * 16 + cl;
          int byteoff = (r * 1024 + c * 2) ^ ((r & 7) << 4);
          *(short*)((char*)tile + byteoff) = f2b(acc[rf][cf][j]);
        }
  }
  __syncthreads();

  if (MODE == 0) {
    // coalesced row-major store
    const int r = t >> 3;
    const int c8 = t & 7;
#pragma unroll
    for (int s = 0; s < 8; ++s) {
      int ci = c8 + 8 * s;
      int byteoff = (r * 1024 + ci * 16) ^ ((r & 7) << 4);
      short8 v = *(const short8*)((const char*)tile + byteoff);
      *(short8*)(outp + (size_t)(rb + r) * 512 + ci * 8) = v;
    }
  } else {
    // k-major fragment pack store
    const int l = lane;
    const int batch = rb >> 12;
    const int jf_base = (rb & 4095) >> 5;
#pragma unroll
    for (int s = 0; s < 8; ++s) {
      int fidx = wid * 8 + s;           // 0..63 = 2 jfrag x 32 cfrag
      int jf = fidx >> 5;
      int cf = fidx & 31;
      int c = cf * 16 + (l & 15);
      int j0 = jf * 32 + 8 * (l >> 4);
      short8 v;
#pragma unroll
      for (int jj = 0; jj < 8; ++jj) {
        int j = j0 + jj;
        int byteoff = (j * 1024 + c * 2) ^ ((j & 7) << 4);
        v[jj] = *(const short*)((const char*)tile + byteoff);
      }
      int bh = batch * 8 + (cf >> 2);
      int cfh = cf & 3;
      int jfg = jf_base + jf;
      *(short8*)(outp + (((size_t)(bh * 128 + jfg) * 4 + cfh) * 64 + l) * 8) = v;
    }
  }
}

// ---------------------------------------------------------------------------
// kv: block = (bh, split of 512 tokens); 4 waves x 4 jfg chunks each.
// Register-accumulated MFMA (no atomics); cross-wave reduce via private LDS
// slots; one fp32 partial per block. ksum accumulated in regs alongside.
// ---------------------------------------------------------------------------
__global__ __launch_bounds__(256)
void kv_kernel(const short* __restrict__ kpack, const short* __restrict__ vpack,
               float* __restrict__ pKV, float* __restrict__ pKS)
{
  __shared__ float red[4][64 * 64];    // 64KB: per-wave partial kv tiles
  __shared__ float ksacc[64];
  const int t = threadIdx.x;
  const int lane = t & 63;
  const int w = t >> 6;
  const int g = lane >> 4;
  const int cl = lane & 15;
  const int bh = blockIdx.x >> 3;
  const int sp = blockIdx.x & 7;
  if (t < 64) ksacc[t] = 0.f;
  __syncthreads();

  f32x4 zero4 = {0.f, 0.f, 0.f, 0.f};
  f32x4 acc[4][4];
#pragma unroll
  for (int df = 0; df < 4; ++df)
#pragma unroll
    for (int cf = 0; cf < 4; ++cf) acc[df][cf] = zero4;
  float ks[4] = {0.f, 0.f, 0.f, 0.f};
  const short8* kp = (const short8*)kpack;
  const short8* vp = (const short8*)vpack;

#pragma unroll
  for (int i = 0; i < 4; ++i) {
    int jfg = sp * 16 + w * 4 + i;
    size_t base = ((size_t)bh * 128 + jfg) * 4 * 64;
    short8 afr[4], bfr[4];
#pragma unroll
    for (int f = 0; f < 4; ++f) {
      afr[f] = vp[base + (size_t)f * 64 + lane];
      bfr[f] = kp[base + (size_t)f * 64 + lane];
    }
#pragma unroll
    for (int cf = 0; cf < 4; ++cf) {
      float s = 0.f;
#pragma unroll
      for (int jj = 0; jj < 8; ++jj) s += b2f(bfr[cf][jj]);
      ks[cf] += s;
    }
#pragma unroll
    for (int df = 0; df < 4; ++df)
#pragma unroll
      for (int cf = 0; cf < 4; ++cf)
        acc[df][cf] = MFMA16x16x32(afr[df], bfr[cf], acc[df][cf]);
  }

  // ksum: reduce over lanes sharing the same cl (g dimension)
#pragma unroll
  for (int cf = 0; cf < 4; ++cf) {
    ks[cf] += __shfl_xor(ks[cf], 16, 64);
    ks[cf] += __shfl_xor(ks[cf], 32, 64);
  }
  if (lane < 16) {
#pragma unroll
    for (int cf = 0; cf < 4; ++cf) atomicAdd(&ksacc[cf * 16 + lane], ks[cf]);
  }

  // write per-wave tile to its private LDS slot (no atomics)
#pragma unroll
  for (int df = 0; df < 4; ++df)
#pragma unroll
    for (int cf = 0; cf < 4; ++cf)
#pragma unroll
      for (int j = 0; j < 4; ++j)
        red[w][(df * 16 + 4 * g + j) * 64 + cf * 16 + cl] = acc[df][cf][j];
  __syncthreads();

  // cross-wave reduce + partial store
  float* dkv = pKV + (size_t)blockIdx.x * 4096;
  for (int i = t; i < 4096; i += 256)
    dkv[i] = red[0][i] + red[1][i] + red[2][i] + red[3][i];
  if (t < 64) pKS[(size_t)blockIdx.x * 64 + t] = ksacc[t];
}

__global__ __launch_bounds__(256)
void kv_reduce(const float* __restrict__ pKV, const float* __restrict__ pKS,
               short* __restrict__ kvT, float* __restrict__ ksum)
{
  const int bh = blockIdx.x;
  const int t = threadIdx.x;
  for (int i = t; i < 4096; i += 256) {
    float s = 0.f;
#pragma unroll
    for (int sp = 0; sp < 8; ++sp) s += pKV[(size_t)(bh * 8 + sp) * 4096 + i];
    kvT[(size_t)bh * 4096 + i] = f2b(s);
  }
  if (t < 64) {
    float s = 0.f;
#pragma unroll
    for (int sp = 0; sp < 8; ++sp) s += pKS[(size_t)(bh * 8 + sp) * 64 + t];
    ksum[bh * 64 + t] = s;
  }
}

// ---------------------------------------------------------------------------
// x: per block (64 rows): z from q.ksum; x = z * q @ kv per head via MFMA
// (kvT gives contiguous B-frags); x -> swizzled LDS -> row-major bf16 store.
// ---------------------------------------------------------------------------
__global__ __launch_bounds__(512)
void x_kernel(const short* __restrict__ qf, const short* __restrict__ kvT,
              const float* __restrict__ ksum, short* __restrict__ xout)
{
  __shared__ short xt[64 * 512];
  __shared__ float ksb[512];
  __shared__ float zb[64 * 8];
  const int t = threadIdx.x;
  const int lane = t & 63;
  const int wid = t >> 6;
  const int wr = wid >> 1;
  const int wc = wid & 1;
  const int g = lane >> 4;
  const int cl = lane & 15;
  const int rb = blockIdx.x << 6;
  const int batch = rb >> 12;

  ksb[t] = ksum[batch * 512 + t];
  __syncthreads();

  // z: one (row, head) pair per thread
  {
    int r = t >> 3, h = t & 7;
    const short8* qrow = (const short8*)(qf + (size_t)(rb + r) * 512 + h * 64);
    float d = 0.f;
#pragma unroll
    for (int c8 = 0; c8 < 8; ++c8) {
      short8 qv = qrow[c8];
#pragma unroll
      for (int jj = 0; jj < 8; ++jj) d += b2f(qv[jj]) * ksb[h * 64 + c8 * 8 + jj];
    }
    zb[r * 8 + h] = 1.f / (d + 1e-6f);
  }
  __syncthreads();

  f32x4 zero4 = {0.f, 0.f, 0.f, 0.f};
  f32x4 xacc[16];
#pragma unroll
  for (int i = 0; i < 16; ++i) xacc[i] = zero4;

  const short8* q8 = (const short8*)qf;
  const size_t qrowbase = (size_t)(rb + wr * 16 + cl) * 64;  // row * 512 / 8
#pragma unroll
  for (int hh = 0; hh < 4; ++hh) {
    int h = wc * 4 + hh;
    short8 af0 = q8[qrowbase + h * 8 + g];
    short8 af1 = q8[qrowbase + h * 8 + 4 + g];
    const short8* kv8 = (const short8*)kvT + ((size_t)(batch * 8 + h)) * 512;
#pragma unroll
    for (int nfl = 0; nfl < 4; ++nfl) {
      short8 b0 = kv8[(size_t)(nfl * 16 + cl) * 8 + g];
      short8 b1 = kv8[(size_t)(nfl * 16 + cl) * 8 + 4 + g];
      int nf = hh * 4 + nfl;
      xacc[nf] = MFMA16x16x32(af0, b0, xacc[nf]);
      xacc[nf] = MFMA16x16x32(af1, b1, xacc[nf]);
    }
  }
  // scale by z and stash x (bf16, swizzled)
#pragma unroll
  for (int hh = 0; hh < 4; ++hh) {
    int h = wc * 4 + hh;
    float z4[4];
#pragma unroll
    for (int j = 0; j < 4; ++j) z4[j] = zb[(wr * 16 + 4 * g + j) * 8 + h];
#pragma unroll
    for (int nfl = 0; nfl < 4; ++nfl) {
      int nf = hh * 4 + nfl;
#pragma unroll
      for (int j = 0; j < 4; ++j) {
        float xv = xacc[nf][j] * z4[j];
        int r = wr * 16 + 4 * g + j;
        int c = wc * 256 + nf * 16 + cl;
        int byteoff = (r * 1024 + c * 2) ^ ((r & 7) << 4);
        *(short*)((char*)xt + byteoff) = f2b(xv);
      }
    }
  }
  __syncthreads();

  // coalesced row-major store
  const int r = t >> 3;
  const int c8 = t & 7;
#pragma unroll
  for (int s = 0; s < 8; ++s) {
    int ci = c8 + 8 * s;
    int byteoff = (r * 1024 + ci * 16) ^ ((r & 7) << 4);
    short8 v = *(const short8*)((const char*)xt + byteoff);
    *(short8*)(xout + (size_t)(rb + r) * 512 + ci * 8) = v;
  }
}

// ---------------------------------------------------------------------------
extern "C" void kernel_launch(void* const* d_in, const int* in_sizes, int n_in,
                              void* d_out, int out_size, void* d_ws, size_t ws_size,
                              hipStream_t stream)
{
  const float* query  = (const float*)d_in[0];
  const float* key_in = (const float*)d_in[1];
  const float* value  = (const float*)d_in[2];
  const float* Wq     = (const float*)d_in[3];
  const float* Wk     = (const float*)d_in[4];
  const float* Wv     = (const float*)d_in[5];
  const float* Wp     = (const float*)d_in[6];
  const float* bp     = (const float*)d_in[7];
  const float* scale  = (const float*)d_in[8];
  float* out = (float*)d_out;

  char* ws = (char*)d_ws;
  size_t off = 0;
  auto alloc = [&](size_t bytes) -> void* {
    void* p = ws + off;
    off += (bytes + 255) & ~(size_t)255;
    return p;
  };
  float* spls  = (float*)alloc(512 * 4);
  short* wpack = (short*)alloc((size_t)4 * 512 * 512 * 2);
  short* qf    = (short*)alloc((size_t)32768 * 512 * 2);
  short* kpack = (short*)alloc((size_t)32768 * 512 * 2);
  short* vpack = (short*)alloc((size_t)32768 * 512 * 2);
  float* pKV   = (float*)alloc((size_t)512 * 4096 * 4);
  float* pKS   = (float*)alloc((size_t)512 * 64 * 4);
  short* kvT   = (short*)alloc((size_t)64 * 4096 * 2);
  float* ksum  = (float*)alloc((size_t)64 * 64 * 4);
  // x reuses kpack: kpack is dead after kv_kernel, x_kernel runs after kv_reduce
  short* xbuf  = kpack;

  prep_kernel<<<65, 256, 0, stream>>>(Wq, Wk, Wv, Wp, scale, wpack, spls);
  proj_kernel<0><<<512, 512, 0, stream>>>(query,  wpack + (size_t)0 * 512 * 512, spls, qf,    nullptr, nullptr);
  proj_kernel<1><<<512, 512, 0, stream>>>(key_in, wpack + (size_t)1 * 512 * 512, spls, kpack, nullptr, nullptr);
  proj_kernel<2><<<512, 512, 0, stream>>>(value,  wpack + (size_t)2 * 512 * 512, spls, vpack, nullptr, nullptr);
  kv_kernel<<<512, 256, 0, stream>>>(kpack, vpack, pKV, pKS);
  kv_reduce<<<64, 256, 0, stream>>>(pKV, pKS, kvT, ksum);
  x_kernel<<<512, 512, 0, stream>>>(qf, kvT, ksum, xbuf);
  proj_kernel<3><<<512, 512, 0, stream>>>(xbuf, wpack + (size_t)3 * 512 * 512, spls, nullptr, bp, out);
}